// Round 9
// baseline (156528.320 us; speedup 1.0000x reference)
//
#include <hip/hip_runtime.h>
#include <cmath>

// ResLSTM+CRF on MI355X, fp32 vector-ALU implementation.
// R9: R6-proven base (k0/k2/k4b/k5 identical to R6; 256x512 geometry everywhere —
// 1024-thr blocks crashed twice (R5/R8) and are banned). k4 changes only:
//  (1) h-weight split: waves 4-5 whh from LDS (k<256, 16 KB), waves 6-7 whh via
//      wave-uniform global loads (scalar path, L2-resident) -> LDS pipe traffic halved.
//  (2) per-layer barrier groups (128 blocks each) coupled via progress words and an
//      8-deep h0 ring: layer1 trails layer0 by 1..7 steps; layer0 throttled at depth 7.
//      Removes the 256-wide per-step jitter coupling. Arithmetic identical to R6.
// Cross-block recurrent arrays only via coherence-point ops (relaxed agent atomic
// stores; global_load_dwordx4 sc0 sc1 + vmcnt). Centralized-release barriers.

namespace {
constexpr int SS = 512;     // seq len
constexpr int BB = 64;      // batch
constexpr int EE = 256;     // embed dim
constexpr int HHd = 256;    // half hidden (bi-lstm)
constexpr int HD = 512;     // hidden (stack)
constexpr int NTAG = 22;
constexpr int TSTART = 20;
constexpr int TSTOP = 21;

// ws offsets (in floats)
constexpr size_t OFF_BI    = 0;                                      // [512][512][64] chunked (ordinary)
constexpr size_t OFF_H1H   = OFF_BI    + (size_t)SS * HD * BB;       // [513][512][64] chunked (coherent)
constexpr size_t OFF_XT    = OFF_H1H   + (size_t)(SS + 1) * HD * BB; // [512][256][64] chunked (ordinary)
constexpr size_t OFF_FEATS = OFF_XT    + (size_t)SS * EE * BB;       // [512][22][64]
constexpr size_t OFF_H0R   = OFF_FEATS + (size_t)SS * NTAG * BB;     // [8][512][64] chunked ring (coherent)
constexpr size_t OFF_HF    = OFF_H0R   + 8 * (size_t)HD * BB;        // [2][256][64] chunked (coherent)
constexpr size_t OFF_HB    = OFF_HF    + 2 * (size_t)HHd * BB;
constexpr size_t OFF_BAR   = OFF_HB    + 2 * (size_t)HHd * BB;       // barrier state (ints)
// barrier ints (relative to OFF_BAR):
//   k2 fwd: flags@0 (128), rel@160 ; k2 bwd: flags@384 (128), rel@544
//   k4 L0: flags@768 (128), rel@904 ; k4 L1: flags@960 (128), rel@1096
//   prog0@1104, prog1@1120
constexpr int BAR_INTS = 1152;
}

__device__ __forceinline__ int cidx(int k, int lane) {
  return ((k >> 2) << 8) + (lane << 2) + (k & 3);
}

// Coherence-point 16B load: bypasses (possibly stale) L1/L2, reads L3/mem.
__device__ __forceinline__ float4 cload4(const float4* p) {
  float4 r;
  asm volatile("global_load_dwordx4 %0, %1, off sc0 sc1" : "=v"(r) : "v"(p));
  return r;
}
__device__ __forceinline__ void vwait0() {
  asm volatile("s_waitcnt vmcnt(0)" ::: "memory");
}
// Coherence-point 4B store (write-through, no dirty line in local L2).
__device__ __forceinline__ void cstore(float* p, float v) {
  __hip_atomic_store(p, v, __ATOMIC_RELAXED, __HIP_MEMORY_SCOPE_AGENT);
}
__device__ __forceinline__ void pstore(int* p, int v) {
  __hip_atomic_store(p, v, __ATOMIC_RELAXED, __HIP_MEMORY_SCOPE_AGENT);
}
__device__ __forceinline__ int pload(const int* p) {
  return __hip_atomic_load(p, __ATOMIC_RELAXED, __HIP_MEMORY_SCOPE_AGENT);
}

// Centralized-release device barrier (R4/R6-proven), no fences.
// Callers must vmcnt-drain their own coherent stores (vwait0) before entering.
template <int NBLK>
__device__ __forceinline__ void gbarC(int* flags, int* release, int bid, int epoch) {
  __syncthreads();
  if (threadIdx.x == 0) {
    pstore(flags + bid, epoch + 1);
  }
  if (bid == 0) {
    if (threadIdx.x < 64) {
      constexpr int PER = NBLK / 64;
      bool ok;
      do {
        ok = true;
#pragma unroll
      for (int i = 0; i < PER; ++i) {
          ok = ok && (pload(flags + threadIdx.x * PER + i) > epoch);
        }
      } while (__any(!ok));
      if (threadIdx.x == 0) {
        pstore(release, epoch + 1);
      }
    }
  } else {
    if (threadIdx.x == 0) {
      while (pload(release) <= epoch) {
        __builtin_amdgcn_s_sleep(1);
      }
    }
  }
  __syncthreads();
}

// Layer-group barrier (128 blocks) with progress publication + cross-group throttle.
// Leader: poll own flags -> publish progSelf=selfVal -> wait progOther>=otherMin
// (skipped if otherMin<=0) -> publish release.
__device__ __forceinline__ void gbarL(int* flags, int* release,
                                      int* progSelf, int selfVal,
                                      int* progOther, int otherMin,
                                      int lb, int epoch) {
  __syncthreads();
  if (threadIdx.x == 0) {
    pstore(flags + lb, epoch + 1);
  }
  if (lb == 0) {
    if (threadIdx.x < 64) {
      bool ok;
      do {
        ok = true;
#pragma unroll
        for (int i = 0; i < 2; ++i)
          ok = ok && (pload(flags + threadIdx.x * 2 + i) > epoch);
      } while (__any(!ok));
      if (threadIdx.x == 0) {
        pstore(progSelf, selfVal);
        if (otherMin > 0) {
          while (pload(progOther) < otherMin) __builtin_amdgcn_s_sleep(2);
        }
        pstore(release, epoch + 1);
      }
    }
  } else {
    if (threadIdx.x == 0) {
      while (pload(release) <= epoch) __builtin_amdgcn_s_sleep(1);
    }
  }
  __syncthreads();
}

__device__ __forceinline__ float sigm(float x) { return 1.f / (1.f + expf(-x)); }
__device__ __forceinline__ float comp4(float4 v, int w) {
  return (w == 0) ? v.x : (w == 1) ? v.y : (w == 2) ? v.z : v.w;
}

// K0: gather embeddings, transpose to chunked [t][e-chunk][lane][4]
__global__ __launch_bounds__(256) void k0(const int* __restrict__ sent,
                                          const float* __restrict__ emb,
                                          float* __restrict__ xT) {
  const int t = blockIdx.x;
  const int lane = threadIdx.x & 63;
  const int w = __builtin_amdgcn_readfirstlane(threadIdx.x >> 6); // 0..3
  __shared__ float tile[64][65];
  __shared__ int rows[64];
  if (threadIdx.x < 64) rows[threadIdx.x] = sent[(size_t)threadIdx.x * SS + t];
  __syncthreads();
  float4* xT4 = (float4*)xT;
  for (int e0 = 0; e0 < EE; e0 += 64) {
    for (int bb = 0; bb < 16; ++bb) {
      int b = bb * 4 + w;
      tile[b][lane] = emb[(size_t)rows[b] * EE + e0 + lane];
    }
    __syncthreads();
    for (int r = 0; r < 4; ++r) {
      int ecl = w * 4 + r;
      int ec = (e0 >> 2) + ecl;
      float4 v = make_float4(tile[lane][ecl * 4 + 0], tile[lane][ecl * 4 + 1],
                             tile[lane][ecl * 4 + 2], tile[lane][ecl * 4 + 3]);
      xT4[((size_t)t * 64 + ec) * 64 + lane] = v;
    }
    __syncthreads();
  }
}

struct K2A {
  const float* xT; float* bi;
  const float* wih_f; const float* whh_f; const float* b_f;
  const float* wih_b; const float* whh_b; const float* b_b;
  const float* h10; const float* c10; const int* lengths;
  float* hf; float* hb;
  int* bar;
};

// K2: BiLSTM (R6-exact). 256 blocks x 512 thr (1 block/CU). Block (d, lb) owns
// units {2lb, 2lb+1} (8 gate rows, r = g*2+ul). All 8 rows of z=[x;h] weights
// (16 KB) staged to LDS. 8 waves partition z into 64-k slices:
// w<4 -> x (xT, ordinary), w>=4 -> h (hbuf ring, coherent).
__global__ __launch_bounds__(512) void k2(K2A a) {
  const int lane = threadIdx.x & 63;
  const int w = __builtin_amdgcn_readfirstlane((int)threadIdx.x >> 6); // 0..7
  const int d = (int)blockIdx.x >> 7;
  const int lb = (int)blockIdx.x & 127;
  int* flags = a.bar + d * 384;
  int* release = a.bar + d * 384 + 160;
  const int u0 = lb * 2;
  const float* wih = d ? a.wih_b : a.wih_f;
  const float* whh = d ? a.whh_b : a.whh_f;
  const float* bias = d ? a.b_b : a.b_f;
  float* hbuf = d ? a.hb : a.hf;

  __shared__ float lw[8 * 512];          // 16 KB: [r][z-k], r = g*2+ul
  __shared__ float4 part[8][2][64];      // 16 KB

  // stage weights: 1024 float4s, 2 per thread
#pragma unroll
  for (int i = 0; i < 2; ++i) {
    int f4 = i * 512 + (int)threadIdx.x; // 0..1023
    int r = f4 >> 7;                     // 128 f4 per row
    int kk = (f4 & 127) * 4;
    int g = r >> 1, ul = r & 1;
    int grow = g * HHd + u0 + ul;
    float4 v = (kk < 256) ? *(const float4*)(wih + (size_t)grow * 256 + kk)
                          : *(const float4*)(whh + (size_t)grow * 256 + (kk - 256));
    *(float4*)(lw + r * 512 + kk) = v;
  }

  const int len = a.lengths[lane];
  float c_st = 0.f, h_old = 0.f;
  if (w < 2) {
    int u = u0 + w;
    h_old = a.h10[d * 256 + u];
    c_st = a.c10[d * 256 + u];
    cstore(&hbuf[cidx(u, lane)], h_old);
    vwait0();
  }
  int ep = 0;
  gbarC<128>(flags, release, lb, ep); ep++;   // entry __syncthreads orders staging

  const int ks = w * 64;                 // z-slice start (0..448)
  const bool hpart = (w >= 4);
  const float4* lw4 = (const float4*)lw;
  int buf = 0;
  for (int step = 0; step < SS; ++step) {
    const int t = d ? (SS - 1 - step) : step;
    const float* actbase = hpart ? (hbuf + (size_t)buf * (HHd * 64))
                                 : (a.xT + (size_t)t * (EE * 64));
    const int ksl = hpart ? (ks - 256) : ks;
    const float4* p = (const float4*)actbase + (size_t)(ksl >> 2) * 64 + lane;
    float4 va[16];
    if (hpart) {
#pragma unroll
      for (int c = 0; c < 16; ++c) va[c] = cload4(p + (size_t)c * 64);
      vwait0();
    } else {
#pragma unroll
      for (int c = 0; c < 16; ++c) va[c] = p[(size_t)c * 64];
    }
    float acc[8] = {0, 0, 0, 0, 0, 0, 0, 0};
#pragma unroll
    for (int c = 0; c < 16; ++c) {
      float4 h = va[c];
#pragma unroll
      for (int r = 0; r < 8; ++r) {
        float4 wv = lw4[r * 128 + (ks >> 2) + c];   // broadcast ds_read_b128
        acc[r] = fmaf(h.x, wv.x, acc[r]);
        acc[r] = fmaf(h.y, wv.y, acc[r]);
        acc[r] = fmaf(h.z, wv.z, acc[r]);
        acc[r] = fmaf(h.w, wv.w, acc[r]);
      }
    }
    part[w][0][lane] = make_float4(acc[0], acc[1], acc[2], acc[3]);
    part[w][1][lane] = make_float4(acc[4], acc[5], acc[6], acc[7]);
    __syncthreads();
    if (w < 2) {
      // acc rows: [0..3] = {i.u0,i.u1,f.u0,f.u1}, [4..7] = {g.u0,g.u1,o.u0,o.u1}
      float qi = 0.f, qf = 0.f, qg = 0.f, qo = 0.f;
#pragma unroll
      for (int wv = 0; wv < 8; ++wv) {
        float4 p0 = part[wv][0][lane], p1 = part[wv][1][lane];
        qi += comp4(p0, w);  qf += comp4(p0, 2 + w);
        qg += comp4(p1, w);  qo += comp4(p1, 2 + w);
      }
      const int u = u0 + w;
      float gi = qi + bias[u];
      float gf = qf + bias[256 + u];
      float gg = qg + bias[512 + u];
      float go = qo + bias[768 + u];
      float i_ = sigm(gi), f_ = sigm(gf), o_ = sigm(go);
      float gn = tanhf(gg);
      float c2 = f_ * c_st + i_ * gn;
      float h2 = o_ * tanhf(c2);
      const bool m = (t < len);
      h2 = m ? h2 : h_old;
      c_st = m ? c2 : c_st;
      h_old = h2;
      cstore(&hbuf[(size_t)(buf ^ 1) * (HHd * 64) + cidx(u, lane)], h2);
      a.bi[(size_t)t * (HD * 64) + cidx(d * 256 + u, lane)] = m ? h2 : 0.f; // ordinary
      vwait0();
    }
    buf ^= 1;
    gbarC<128>(flags, release, lb, ep); ep++;
  }
}

struct K4A {
  const float* bi; float* h0r; float* h1h;
  const float* wihs; const float* whhs; const float* bs;
  const float* h20; const float* c20;
  int* bar;
};

// K4: 2-layer stack LSTM with per-layer barrier groups (128 blocks each).
// 256 blocks x 512 thr (proven geometry). Block (layer = bid>>7, lb = bid&127)
// owns units 4lb..4lb+3 (16 gate rows, r = g*4+ul). 8 waves x 128-k slices:
//   w 0..3 -> x part (layer0: bi[t] ordinary; layer1: h0 ring coherent); wih global.
//   w 4..5 -> h part k<256, whh from LDS (16 KB staged).
//   w 6..7 -> h part k>=256, whh from global (wave-uniform -> scalar path, L2).
// Layer0 iteration it computes h0(it) -> h0 ring slot it&7 (8-deep).
// Layer1 iteration it computes h1(it) from h0(it) + h1(it-1) -> h1h[it+1].
// Coupling: prog0/prog1 words; layer1 waits prog0 >= it+1; layer0 throttled so it
// never overwrites a ring slot layer1 hasn't consumed (prog1 >= e-7).
__global__ __launch_bounds__(512) void k4(K4A a) {
  const int lane = threadIdx.x & 63;
  const int w = __builtin_amdgcn_readfirstlane((int)threadIdx.x >> 6);  // 0..7
  const int layer = (int)blockIdx.x >> 7;
  const int lb = (int)blockIdx.x & 127;
  const int u0 = lb * 4;
  const float* wih = a.wihs + (size_t)layer * (2048 * 512);
  const float* whh = a.whhs + (size_t)layer * (2048 * 512);

  int* flags    = a.bar + (layer ? 192 : 0);
  int* release  = a.bar + (layer ? 328 : 136);
  int* progSelf = a.bar + (layer ? 352 : 336);
  int* progOther= a.bar + (layer ? 336 : 352);

  __shared__ float lwh[16 * 256];        // 16 KB: whh rows, h-k in [0,256)
  __shared__ float part[4][16][64];      // 16 KB

  // stage lwh: 1024 float4s, 2 per thread
#pragma unroll
  for (int i = 0; i < 2; ++i) {
    int f4 = i * 512 + (int)threadIdx.x; // 0..1023
    int r = f4 >> 6;                     // 64 f4 per row (k<256)
    int kk = (f4 & 63) * 4;
    int g = r >> 2, ul = r & 3;
    *(float4*)(lwh + r * 256 + kk) =
        *(const float4*)(whh + (size_t)(g * HD + u0 + ul) * 512 + kk);
  }

  const bool hpart = (w >= 4);
  const bool ldsw = (w == 4 || w == 5);
  const int slz = hpart ? (w - 4) * 128 : w * 128;   // k-slice start within part
  const float* wr[16];
  {
    const float* wsrc = hpart ? whh : wih;
#pragma unroll
    for (int g = 0; g < 4; ++g)
#pragma unroll
      for (int ul = 0; ul < 4; ++ul)
        wr[g * 4 + ul] = wsrc + (size_t)(g * HD + u0 + ul) * HD + slz;
  }

  float c_st = 0.f;
  if (w < 4) {
    const int u = u0 + w;
    c_st = a.c20[layer * 512 + u];
    float h0i = a.h20[layer * 512 + u];
    if (layer == 0) cstore(&a.h0r[(size_t)7 * (HD * 64) + cidx(u, lane)], h0i); // h0(-1) slot 7
    else            cstore(&a.h1h[cidx(u, lane)], h0i);                          // h1(-1) slot 0
    vwait0();
  }
  // init barrier, epoch 0. L0: no throttle. L1: wait prog0 >= 1 (h0(0) ready).
  gbarL(flags, release, progSelf, 0, progOther, layer ? 1 : 0, lb, 0);

  const float4* lwh4 = (const float4*)lwh;
  for (int it = 0; it < SS; ++it) {
    const float4* p;
    bool coh;
    if (layer == 0) {
      if (hpart) { p = (const float4*)(a.h0r + (size_t)((it + 7) & 7) * (HD * 64)); coh = true; }
      else       { p = (const float4*)(a.bi + (size_t)it * (HD * 64)); coh = false; }
    } else {
      if (hpart) p = (const float4*)(a.h1h + (size_t)it * (HD * 64));       // h1(it-1)
      else       p = (const float4*)(a.h0r + (size_t)(it & 7) * (HD * 64)); // h0(it)
      coh = true;
    }
    p += (size_t)(slz >> 2) * 64 + lane;
    float acc[16] = {0, 0, 0, 0, 0, 0, 0, 0, 0, 0, 0, 0, 0, 0, 0, 0};
#pragma unroll
    for (int gseg = 0; gseg < 2; ++gseg) {
      float4 va[16];
      const float4* pg = p + (size_t)gseg * 16 * 64;
      if (coh) {
#pragma unroll
        for (int c = 0; c < 16; ++c) va[c] = cload4(pg + (size_t)c * 64);
        vwait0();
      } else {
#pragma unroll
        for (int c = 0; c < 16; ++c) va[c] = pg[(size_t)c * 64];
      }
#pragma unroll
      for (int c16 = 0; c16 < 16; ++c16) {
        const int kc = gseg * 16 + c16;        // f4 chunk within 128-k slice
        float4 h = va[c16];
#pragma unroll
        for (int r = 0; r < 16; ++r) {
          float4 wv = ldsw ? lwh4[r * 64 + (slz >> 2) + kc]
                           : *(const float4*)(wr[r] + kc * 4);
          acc[r] = fmaf(h.x, wv.x, acc[r]);
          acc[r] = fmaf(h.y, wv.y, acc[r]);
          acc[r] = fmaf(h.z, wv.z, acc[r]);
          acc[r] = fmaf(h.w, wv.w, acc[r]);
        }
      }
    }
    // 2-stage cross-wave reduction: waves 0-3 write, waves 4-7 add.
    if (w < 4) {
#pragma unroll
      for (int r = 0; r < 16; ++r) part[w][r][lane] = acc[r];
    }
    __syncthreads();
    if (w >= 4) {
#pragma unroll
      for (int r = 0; r < 16; ++r) part[w - 4][r][lane] += acc[r];
    }
    __syncthreads();
    if (w < 4) {
      // unit u = u0 + w; gate g: row r = g*4 + w, summed over 4 slice-slots
      float q[4];
#pragma unroll
      for (int g = 0; g < 4; ++g) {
        float s = 0.f;
#pragma unroll
        for (int slot = 0; slot < 4; ++slot) s += part[slot][g * 4 + w][lane];
        q[g] = s;
      }
      const int u = u0 + w;
      const float* bsl = a.bs + (size_t)layer * 2048;
      float gi = q[0] + bsl[u];
      float gf = q[1] + bsl[512 + u];
      float gg = q[2] + bsl[1024 + u];
      float go = q[3] + bsl[1536 + u];
      float i_ = sigm(gi), f_ = sigm(gf), o_ = sigm(go);
      float gn = tanhf(gg);
      float c2 = f_ * c_st + i_ * gn;
      float h2 = o_ * tanhf(c2);
      c_st = c2;
      if (layer == 0)
        cstore(&a.h0r[(size_t)(it & 7) * (HD * 64) + cidx(u, lane)], h2);   // h0(it)
      else
        cstore(&a.h1h[(size_t)(it + 1) * (HD * 64) + cidx(u, lane)], h2);   // h1(it)
      vwait0();
    }
    const int e = it + 1;
    int otherMin;
    if (layer == 0) otherMin = e - 7;                    // ring-depth throttle
    else            otherMin = (it == SS - 1) ? 0 : e + 1; // need h0(it+1) next iter
    gbarL(flags, release, progSelf, e, progOther, otherMin, lb, e);
  }
}

// K4b: feats[t][j][b] = h1(t) . W_tag[j] + b_tag[j]
__global__ __launch_bounds__(256) void k4b(const float* __restrict__ h1h,
                                           const float* __restrict__ Wtag,
                                           const float* __restrict__ btag,
                                           float* __restrict__ feats) {
  const int t = blockIdx.x;
  const int lane = threadIdx.x & 63;
  const int w = __builtin_amdgcn_readfirstlane(threadIdx.x >> 6);
  const int j0 = w * 6;
  const float4* p = (const float4*)(h1h + (size_t)(t + 1) * (HD * 64)) + lane;
  const float* r[6];
  float acc[6];
#pragma unroll
  for (int jj = 0; jj < 6; ++jj) {
    int j = j0 + jj; if (j > 21) j = 21;
    r[jj] = Wtag + (size_t)j * HD;
    acc[jj] = btag[j];
  }
#pragma unroll 2
  for (int c = 0; c < 128; ++c) {
    float4 h = p[(size_t)c * 64];
    int k = c * 4;
#pragma unroll
    for (int jj = 0; jj < 6; ++jj) {
      acc[jj] = fmaf(h.x, r[jj][k], acc[jj]);
      acc[jj] = fmaf(h.y, r[jj][k + 1], acc[jj]);
      acc[jj] = fmaf(h.z, r[jj][k + 2], acc[jj]);
      acc[jj] = fmaf(h.w, r[jj][k + 3], acc[jj]);
    }
  }
#pragma unroll
  for (int jj = 0; jj < 6; ++jj) {
    int j = j0 + jj;
    if (j < NTAG) feats[((size_t)t * NTAG + j) * 64 + lane] = acc[jj];
  }
}

// K5: Viterbi decode, one block per batch element, backpointers in LDS.
__global__ __launch_bounds__(64) void k5(const float* __restrict__ feats,
                                         const float* __restrict__ trans,
                                         const int* __restrict__ lengths,
                                         float* __restrict__ out) {
  const int b = blockIdx.x;
  const int j = threadIdx.x;
  __shared__ float tr[NTAG * NTAG];
  __shared__ float sc[NTAG];
  __shared__ float term[NTAG];
  __shared__ unsigned char bp[SS - 1][NTAG];
  for (int i = j; i < NTAG * NTAG; i += 64) tr[i] = trans[i];
  const int len = lengths[b];
  float score = 0.f;
  __syncthreads();
  if (j < NTAG) {
    score = feats[(size_t)j * 64 + b] + tr[j * NTAG + TSTART];
    sc[j] = score;
  }
  __syncthreads();
  for (int t = 1; t < len; ++t) {
    float best = -3.4e38f; int bi_ = 0;
    if (j < NTAG) {
#pragma unroll
      for (int i = 0; i < NTAG; ++i) {
        float c = sc[i] + tr[j * NTAG + i];
        if (c > best) { best = c; bi_ = i; }   // strict > keeps first max
      }
      score = best + feats[((size_t)t * NTAG + j) * 64 + b];
      bp[t - 1][j] = (unsigned char)bi_;
    }
    __syncthreads();
    if (j < NTAG) sc[j] = score;
    __syncthreads();
  }
  if (j < NTAG) term[j] = score + tr[TSTOP * NTAG + j];
  __syncthreads();
  if (j == 0) {
    float bs = term[0]; int bt = 0;
    for (int i = 1; i < NTAG; ++i) if (term[i] > bs) { bs = term[i]; bt = i; }
    out[b] = bs;
    int tag = bt;
    for (int t = SS - 1; t >= 1; --t) {
      out[64 + (size_t)b * SS + t] = (float)tag;
      if (t < len) tag = bp[t - 1][tag];
    }
    out[64 + (size_t)b * SS + 0] = (float)tag;
  }
}

extern "C" void kernel_launch(void* const* d_in, const int* in_sizes, int n_in,
                              void* d_out, int out_size, void* d_ws, size_t ws_size,
                              hipStream_t stream) {
  const int* sentence = (const int*)d_in[0];
  const int* lengths  = (const int*)d_in[1];
  const float* emb    = (const float*)d_in[2];
  const float* wih_f  = (const float*)d_in[3];
  const float* whh_f  = (const float*)d_in[4];
  const float* b_f    = (const float*)d_in[5];
  const float* wih_b  = (const float*)d_in[6];
  const float* whh_b  = (const float*)d_in[7];
  const float* b_b    = (const float*)d_in[8];
  const float* h10    = (const float*)d_in[9];
  const float* c10    = (const float*)d_in[10];
  const float* wihs   = (const float*)d_in[11];
  const float* whhs   = (const float*)d_in[12];
  const float* bs     = (const float*)d_in[13];
  const float* h20    = (const float*)d_in[14];
  const float* c20    = (const float*)d_in[15];
  const float* Wtag   = (const float*)d_in[16];
  const float* btag   = (const float*)d_in[17];
  const float* trans  = (const float*)d_in[18];
  float* ws = (float*)d_ws;
  float* out = (float*)d_out;
  int* barbase = (int*)(ws + OFF_BAR);

  // zero barrier state (ws is poisoned 0xAA before every call)
  hipMemsetAsync((void*)barbase, 0, BAR_INTS * sizeof(int), stream);

  k0<<<dim3(SS), dim3(256), 0, stream>>>(sentence, emb, ws + OFF_XT);

  K2A a2{ws + OFF_XT, ws + OFF_BI, wih_f, whh_f, b_f, wih_b, whh_b, b_b,
         h10, c10, lengths,
         ws + OFF_HF, ws + OFF_HB,
         barbase};
  k2<<<dim3(256), dim3(512), 0, stream>>>(a2);

  K4A a4{ws + OFF_BI, ws + OFF_H0R, ws + OFF_H1H, wihs, whhs, bs, h20, c20,
         barbase + 768};
  k4<<<dim3(256), dim3(512), 0, stream>>>(a4);

  k4b<<<dim3(SS), dim3(256), 0, stream>>>(ws + OFF_H1H, Wtag, btag, ws + OFF_FEATS);
  k5<<<dim3(BB), dim3(64), 0, stream>>>(ws + OFF_FEATS, trans, lengths, out);
}